// Round 2
// baseline (600.369 us; speedup 1.0000x reference)
//
#include <hip/hip_runtime.h>
#include <stdint.h>

#define D_MEM 2048
#define BATCH 4096
#define K_DIM 4096   // 2*D
#define N_DIM 8192   // 4*D

typedef __bf16 bf16x8 __attribute__((ext_vector_type(8)));
typedef float f32x4 __attribute__((ext_vector_type(4)));

typedef const void __attribute__((address_space(1)))* gas_t;
typedef void __attribute__((address_space(3)))* las_t;

__device__ __forceinline__ ushort f2b(float f) {
  union { float f; uint32_t u; } v; v.f = f;
  uint32_t u = v.u + 0x7fffu + ((v.u >> 16) & 1u);
  return (ushort)(u >> 16);
}
__device__ __forceinline__ float sigm(float x) {
  return 1.0f / (1.0f + __expf(-x));
}
__device__ __forceinline__ float fast_tanh(float x) {
  float xx = fminf(fmaxf(x, -15.f), 15.f);
  float t = __expf(-2.f * xx);
  return (1.f - t) / (1.f + t);
}

// ---------------------------------------------------------------------------
// Kernel 1: cast+concat  A[m][k] = bf16( k<D ? lh[m][k] : rh[m][k-D] )
// ---------------------------------------------------------------------------
__global__ void cast_concat_kernel(const float* __restrict__ lh,
                                   const float* __restrict__ rh,
                                   ushort* __restrict__ A) {
  int i4 = blockIdx.x * 256 + threadIdx.x;     // 4096*1024 float4 groups
  int row = i4 >> 10;
  int col = (i4 & 1023) * 4;
  const float* src = (col < D_MEM) ? (lh + (size_t)row * D_MEM + col)
                                   : (rh + (size_t)row * D_MEM + (col - D_MEM));
  float4 v = *(const float4*)src;
  ushort4 o; o.x = f2b(v.x); o.y = f2b(v.y); o.z = f2b(v.z); o.w = f2b(v.w);
  *(ushort4*)(A + (size_t)row * K_DIM + col) = o;
}

// ---------------------------------------------------------------------------
// Kernel 2: transpose+cast with gate-interleaved N permutation.
//   W col n = g*2048 + j  (g = gate, j = output col)
//   Bt row n' = (j>>5)*128 + ((j>>4)&1)*64 + g*16 + (j&15)
// so that in the GEMM, a wave's 4 fragment tiles (16 cols each) are the
// 4 gates of the SAME 16 output columns -> gating fuses into the epilogue
// with zero cross-lane traffic.
// ---------------------------------------------------------------------------
__global__ void transpose_cast_kernel(const float* __restrict__ Wl,
                                      const float* __restrict__ Wr,
                                      ushort* __restrict__ Bt) {
  __shared__ float t[64 * 65];
  const float* W = blockIdx.z ? Wr : Wl;
  int n0 = blockIdx.x * 64;     // W-column base (within one gate: 2048%64==0)
  int k0 = blockIdx.y * 64;
  int tid = threadIdx.x;
#pragma unroll
  for (int i = 0; i < 4; ++i) {
    int idx = i * 256 + tid;
    int rr = idx >> 4;            // k-local row 0..63
    int c4 = (idx & 15) * 4;      // n-local col
    float4 v = *(const float4*)(W + (size_t)(k0 + rr) * N_DIM + n0 + c4);
    t[rr * 65 + c4 + 0] = v.x;
    t[rr * 65 + c4 + 1] = v.y;
    t[rr * 65 + c4 + 2] = v.z;
    t[rr * 65 + c4 + 3] = v.w;
  }
  __syncthreads();
  int kbase = (blockIdx.z ? D_MEM : 0) + k0;
  int g  = n0 >> 11;            // gate index 0..3
  int jb = n0 & 2047;           // output-col base
#pragma unroll
  for (int i = 0; i < 4; ++i) {
    int idx = i * 256 + tid;
    int rr = idx >> 4;            // n-local row 0..63
    int c4 = (idx & 15) * 4;      // k-local col
    int j = jb + rr;
    int np = ((j >> 5) << 7) + (((j >> 4) & 1) << 6) + (g << 4) + (j & 15);
    ushort4 o;
    o.x = f2b(t[(c4 + 0) * 65 + rr]);
    o.y = f2b(t[(c4 + 1) * 65 + rr]);
    o.z = f2b(t[(c4 + 2) * 65 + rr]);
    o.w = f2b(t[(c4 + 3) * 65 + rr]);
    *(ushort4*)(Bt + (size_t)np * K_DIM + kbase + c4) = o;
  }
}

// ---------------------------------------------------------------------------
// Kernel 3: GEMM + fused gating epilogue.
// 128x128 tile, BK=64, 4 waves (2x2), 16x16x32 MFMA, global_load_lds staging.
// acc[i][g][e] = gate-g pre-activation for (row m, output col colb).
// Epilogue: g += bl+br; c = sig(i)*tanh(u)+sig(lf)*lc+sig(rf)*rc; h=tanh(c).
// ---------------------------------------------------------------------------
__global__ __launch_bounds__(256) void gemm_gate_kernel(
    const ushort* __restrict__ A,   // [M][K] bf16
    const ushort* __restrict__ B,   // [N'][K] bf16 (permuted)
    const float* __restrict__ bl,
    const float* __restrict__ br,
    const float* __restrict__ lc,
    const float* __restrict__ rc,
    float* __restrict__ out) {      // [c ; h] fp32
  const int K = K_DIM;
  __shared__ ushort As[128 * 64];
  __shared__ ushort Bs[128 * 64];
  int tid = threadIdx.x;
  int lane = tid & 63;
  int wave = tid >> 6;
  int wm = wave >> 1, wn = wave & 1;
  int q = lane >> 4, r = lane & 15;
  int m0 = blockIdx.y * 128, n0 = blockIdx.x * 128;

  // staging: slot s = t*256 + tid ; row = s/8 , c' = s%8 , c = c' ^ (row&7)
  int c_chunk = (tid & 7) ^ ((tid >> 3) & 7);
  int srow = tid >> 3;
  const ushort* pA = A + (size_t)(m0 + srow) * K + c_chunk * 8;
  const ushort* pB = B + (size_t)(n0 + srow) * K + c_chunk * 8;

  int aoff[4], boff[4];
#pragma unroll
  for (int f = 0; f < 4; ++f) {
    int ml = wm * 64 + f * 16 + r;
    aoff[f] = (ml * 8 + (q ^ (ml & 7))) * 16;
    int nl = wn * 64 + f * 16 + r;
    boff[f] = (nl * 8 + (q ^ (nl & 7))) * 16;
  }

  f32x4 acc[4][4];
#pragma unroll
  for (int i = 0; i < 4; ++i)
#pragma unroll
    for (int j = 0; j < 4; ++j) acc[i][j] = f32x4{0.f, 0.f, 0.f, 0.f};

  char* AsB = (char*)As;
  char* BsB = (char*)Bs;
  int ldsbase = wave * 1024;  // bytes; round t adds t*4096

  for (int kt = 0; kt < K / 64; ++kt) {
#pragma unroll
    for (int t2 = 0; t2 < 4; ++t2)
      __builtin_amdgcn_global_load_lds((gas_t)(pA + (size_t)t2 * 32 * K),
                                       (las_t)(AsB + t2 * 4096 + ldsbase),
                                       16, 0, 0);
#pragma unroll
    for (int t2 = 0; t2 < 4; ++t2)
      __builtin_amdgcn_global_load_lds((gas_t)(pB + (size_t)t2 * 32 * K),
                                       (las_t)(BsB + t2 * 4096 + ldsbase),
                                       16, 0, 0);
    __syncthreads();
#pragma unroll
    for (int ks = 0; ks < 2; ++ks) {
      bf16x8 af[4], bg[4];
#pragma unroll
      for (int f = 0; f < 4; ++f) {
        af[f] = *(const bf16x8*)(AsB + (aoff[f] ^ (ks * 64)));
        bg[f] = *(const bf16x8*)(BsB + (boff[f] ^ (ks * 64)));
      }
#pragma unroll
      for (int i = 0; i < 4; ++i)
#pragma unroll
        for (int j = 0; j < 4; ++j)
          acc[i][j] = __builtin_amdgcn_mfma_f32_16x16x32_bf16(
              af[i], bg[j], acc[i][j], 0, 0, 0);
    }
    __syncthreads();
    pA += 64;
    pB += 64;
  }

  // ---- fused gating epilogue (all four gates live in this lane's regs) ----
  int colb = (blockIdx.x << 5) + (wn << 4) + r;   // output col 0..2047
  float bsum0 = bl[0 * D_MEM + colb] + br[0 * D_MEM + colb];
  float bsum1 = bl[1 * D_MEM + colb] + br[1 * D_MEM + colb];
  float bsum2 = bl[2 * D_MEM + colb] + br[2 * D_MEM + colb];
  float bsum3 = bl[3 * D_MEM + colb] + br[3 * D_MEM + colb];
  float* outc = out;
  float* outh = out + (size_t)BATCH * D_MEM;
#pragma unroll
  for (int i = 0; i < 4; ++i) {
    int mb = m0 + wm * 64 + i * 16 + q * 4;
#pragma unroll
    for (int e = 0; e < 4; ++e) {
      size_t off = (size_t)(mb + e) * D_MEM + colb;
      float gi = acc[i][0][e] + bsum0;
      float gf = acc[i][1][e] + bsum1;
      float gr = acc[i][2][e] + bsum2;
      float gu = acc[i][3][e] + bsum3;
      float cc = sigm(gi) * fast_tanh(gu) + sigm(gf) * lc[off] + sigm(gr) * rc[off];
      outc[off] = cc;
      outh[off] = fast_tanh(cc);
    }
  }
}

// ---------------------------------------------------------------------------
extern "C" void kernel_launch(void* const* d_in, const int* in_sizes, int n_in,
                              void* d_out, int out_size, void* d_ws, size_t ws_size,
                              hipStream_t stream) {
  const float* lc = (const float*)d_in[0];
  const float* lh = (const float*)d_in[1];
  const float* rc = (const float*)d_in[2];
  const float* rh = (const float*)d_in[3];
  const float* Wl = (const float*)d_in[4];
  const float* bl = (const float*)d_in[5];
  const float* Wr = (const float*)d_in[6];
  const float* br = (const float*)d_in[7];
  float* out = (float*)d_out;

  char* ws = (char*)d_ws;
  ushort* A  = (ushort*)ws;                                // 32 MB  bf16 [4096][4096]
  ushort* Bt = (ushort*)(ws + (size_t)32 * 1024 * 1024);   // 64 MB  bf16 [8192][4096]

  cast_concat_kernel<<<16384, 256, 0, stream>>>(lh, rh, A);
  dim3 tg(128, 32, 2);
  transpose_cast_kernel<<<tg, 256, 0, stream>>>(Wl, Wr, Bt);
  dim3 gg(64, 32);
  gemm_gate_kernel<<<gg, 256, 0, stream>>>(A, Bt, bl, br, lc, rc, out);
}

// Round 3
// 555.668 us; speedup vs baseline: 1.0804x; 1.0804x over previous
//
#include <hip/hip_runtime.h>
#include <stdint.h>

#define D_MEM 2048
#define BATCH 4096
#define K_DIM 4096   // 2*D
#define N_DIM 8192   // 4*D

typedef __bf16 bf16x8 __attribute__((ext_vector_type(8)));
typedef float f32x4 __attribute__((ext_vector_type(4)));

typedef const void __attribute__((address_space(1)))* gas_t;
typedef void __attribute__((address_space(3)))* las_t;

__device__ __forceinline__ ushort f2b(float f) {
  union { float f; uint32_t u; } v; v.f = f;
  uint32_t u = v.u + 0x7fffu + ((v.u >> 16) & 1u);
  return (ushort)(u >> 16);
}
__device__ __forceinline__ float sigm(float x) {
  return __builtin_amdgcn_rcpf(1.0f + __expf(-x));
}
__device__ __forceinline__ float fast_tanh(float x) {
  float xx = fminf(fmaxf(x, -15.f), 15.f);
  float t = __expf(-2.f * xx);
  return (1.f - t) * __builtin_amdgcn_rcpf(1.f + t);
}

// ---------------------------------------------------------------------------
// Kernel 1: cast+concat  A[m][k] = bf16( k<D ? lh[m][k] : rh[m][k-D] )
// grid-stride: 2048 blocks x 256 threads x 8 float4
// ---------------------------------------------------------------------------
__global__ void cast_concat_kernel(const float* __restrict__ lh,
                                   const float* __restrict__ rh,
                                   ushort* __restrict__ A) {
#pragma unroll
  for (int it = 0; it < 8; ++it) {
    int i4 = blockIdx.x * 2048 + it * 256 + threadIdx.x;  // 4096*1024 groups
    int row = i4 >> 10;
    int col = (i4 & 1023) * 4;
    const float* src = (col < D_MEM) ? (lh + (size_t)row * D_MEM + col)
                                     : (rh + (size_t)row * D_MEM + (col - D_MEM));
    float4 v = *(const float4*)src;
    ushort4 o; o.x = f2b(v.x); o.y = f2b(v.y); o.z = f2b(v.z); o.w = f2b(v.w);
    *(ushort4*)(A + (size_t)row * K_DIM + col) = o;
  }
}

// ---------------------------------------------------------------------------
// Kernel 2: transpose+cast with gate-interleaved N permutation.
//   W col n = g*2048 + j  ->  Bt row n' = (j>>5)*128 + ((j>>4)&1)*64 + g*16 + (j&15)
// ---------------------------------------------------------------------------
__global__ void transpose_cast_kernel(const float* __restrict__ Wl,
                                      const float* __restrict__ Wr,
                                      ushort* __restrict__ Bt) {
  __shared__ float t[64 * 65];
  const float* W = blockIdx.z ? Wr : Wl;
  int n0 = blockIdx.x * 64;
  int k0 = blockIdx.y * 64;
  int tid = threadIdx.x;
#pragma unroll
  for (int i = 0; i < 4; ++i) {
    int idx = i * 256 + tid;
    int rr = idx >> 4;            // k-local row
    int c4 = (idx & 15) * 4;      // n-local col
    float4 v = *(const float4*)(W + (size_t)(k0 + rr) * N_DIM + n0 + c4);
    t[rr * 65 + c4 + 0] = v.x;
    t[rr * 65 + c4 + 1] = v.y;
    t[rr * 65 + c4 + 2] = v.z;
    t[rr * 65 + c4 + 3] = v.w;
  }
  __syncthreads();
  int kbase = (blockIdx.z ? D_MEM : 0) + k0;
  int g  = n0 >> 11;
  int jb = n0 & 2047;
#pragma unroll
  for (int i = 0; i < 4; ++i) {
    int idx = i * 256 + tid;
    int rr = idx >> 4;            // n-local row
    int c4 = (idx & 15) * 4;      // k-local col
    int j = jb + rr;
    int np = ((j >> 5) << 7) + (((j >> 4) & 1) << 6) + (g << 4) + (j & 15);
    ushort4 o;
    o.x = f2b(t[(c4 + 0) * 65 + rr]);
    o.y = f2b(t[(c4 + 1) * 65 + rr]);
    o.z = f2b(t[(c4 + 2) * 65 + rr]);
    o.w = f2b(t[(c4 + 3) * 65 + rr]);
    *(ushort4*)(Bt + (size_t)np * K_DIM + kbase + c4) = o;
  }
}

// ---------------------------------------------------------------------------
// Kernel 3: GEMM + fused gating epilogue (LDS-staged, coalesced).
// ---------------------------------------------------------------------------
// swizzled LDS slot for a 128x32 fp32 tile, 2-way-max banks on both phases
__device__ __forceinline__ int sw(int row, int col) {
  return row * 32 + ((((col >> 2) ^ (row & 7)) << 2) | (col & 3));
}

__global__ __launch_bounds__(256) void gemm_gate_kernel(
    const ushort* __restrict__ A,   // [M][K] bf16
    const ushort* __restrict__ B,   // [N'][K] bf16 (permuted)
    const float* __restrict__ bl,
    const float* __restrict__ br,
    const float* __restrict__ lc,
    const float* __restrict__ rc,
    float* __restrict__ out) {      // [c ; h] fp32
  const int K = K_DIM;
  __shared__ __align__(16) char smem[32768];
  float* smemF = (float*)smem;
  int tid = threadIdx.x;
  int lane = tid & 63;
  int wave = tid >> 6;
  int wm = wave >> 1, wn = wave & 1;
  int q = lane >> 4, r = lane & 15;
  int m0 = blockIdx.y * 128, n0 = blockIdx.x * 128;

  int c_chunk = (tid & 7) ^ ((tid >> 3) & 7);
  int srow = tid >> 3;
  const ushort* pA = A + (size_t)(m0 + srow) * K + c_chunk * 8;
  const ushort* pB = B + (size_t)(n0 + srow) * K + c_chunk * 8;

  int aoff[4], boff[4];
#pragma unroll
  for (int f = 0; f < 4; ++f) {
    int ml = wm * 64 + f * 16 + r;
    aoff[f] = (ml * 8 + (q ^ (ml & 7))) * 16;
    int nl = wn * 64 + f * 16 + r;
    boff[f] = (nl * 8 + (q ^ (nl & 7))) * 16;
  }

  f32x4 acc[4][4];
#pragma unroll
  for (int i = 0; i < 4; ++i)
#pragma unroll
    for (int j = 0; j < 4; ++j) acc[i][j] = f32x4{0.f, 0.f, 0.f, 0.f};

  char* AsB = smem;
  char* BsB = smem + 16384;
  int ldsbase = wave * 1024;

  for (int kt = 0; kt < K / 64; ++kt) {
#pragma unroll
    for (int t2 = 0; t2 < 4; ++t2)
      __builtin_amdgcn_global_load_lds((gas_t)(pA + (size_t)t2 * 32 * K),
                                       (las_t)(AsB + t2 * 4096 + ldsbase),
                                       16, 0, 0);
#pragma unroll
    for (int t2 = 0; t2 < 4; ++t2)
      __builtin_amdgcn_global_load_lds((gas_t)(pB + (size_t)t2 * 32 * K),
                                       (las_t)(BsB + t2 * 4096 + ldsbase),
                                       16, 0, 0);
    __syncthreads();
#pragma unroll
    for (int ks = 0; ks < 2; ++ks) {
      bf16x8 af[4], bg[4];
#pragma unroll
      for (int f = 0; f < 4; ++f) {
        af[f] = *(const bf16x8*)(AsB + (aoff[f] ^ (ks * 64)));
        bg[f] = *(const bf16x8*)(BsB + (boff[f] ^ (ks * 64)));
      }
#pragma unroll
      for (int i = 0; i < 4; ++i)
#pragma unroll
        for (int j = 0; j < 4; ++j)
          acc[i][j] = __builtin_amdgcn_mfma_f32_16x16x32_bf16(
              af[i], bg[j], acc[i][j], 0, 0, 0);
    }
    __syncthreads();
    pA += 64;
    pB += 64;
  }

  // ---- fused gating epilogue ----
  // Phase 1: coop coalesced load of lc/rc tiles (128 rows x 32 cols fp32 each)
  float* S = smemF;          // lc tile -> becomes c tile
  float* T = smemF + 4096;   // rc tile -> becomes h tile
  int c0 = blockIdx.x * 32;
#pragma unroll
  for (int it = 0; it < 4; ++it) {
    int idx = it * 256 + tid;       // 0..1023
    int rrow = idx >> 3;            // 0..127
    int cc4 = (idx & 7) * 4;
    int slot = sw(rrow, cc4);
    size_t goff = (size_t)(m0 + rrow) * D_MEM + c0 + cc4;
    *(float4*)(S + slot) = *(const float4*)(lc + goff);
    *(float4*)(T + slot) = *(const float4*)(rc + goff);
  }
  __syncthreads();

  // Phase 2: gate math in MFMA layout; overwrite own slots with c,h
  int colL = wn * 16 + r;           // tile-local output col
  int colb = c0 + colL;             // global output col
  float bsum0 = bl[0 * D_MEM + colb] + br[0 * D_MEM + colb];
  float bsum1 = bl[1 * D_MEM + colb] + br[1 * D_MEM + colb];
  float bsum2 = bl[2 * D_MEM + colb] + br[2 * D_MEM + colb];
  float bsum3 = bl[3 * D_MEM + colb] + br[3 * D_MEM + colb];
#pragma unroll
  for (int i = 0; i < 4; ++i) {
    int rbase = wm * 64 + i * 16 + q * 4;
#pragma unroll
    for (int e = 0; e < 4; ++e) {
      int slot = sw(rbase + e, colL);
      float gi = acc[i][0][e] + bsum0;
      float gf = acc[i][1][e] + bsum1;
      float gr = acc[i][2][e] + bsum2;
      float gu = acc[i][3][e] + bsum3;
      float cc = sigm(gi) * fast_tanh(gu) + sigm(gf) * S[slot] + sigm(gr) * T[slot];
      S[slot] = cc;
      T[slot] = fast_tanh(cc);
    }
  }
  __syncthreads();

  // Phase 3: coop coalesced store of c/h tiles
  float* outc = out;
  float* outh = out + (size_t)BATCH * D_MEM;
#pragma unroll
  for (int it = 0; it < 4; ++it) {
    int idx = it * 256 + tid;
    int rrow = idx >> 3;
    int cc4 = (idx & 7) * 4;
    int slot = sw(rrow, cc4);
    size_t goff = (size_t)(m0 + rrow) * D_MEM + c0 + cc4;
    *(float4*)(outc + goff) = *(float4*)(S + slot);
    *(float4*)(outh + goff) = *(float4*)(T + slot);
  }
}

// ---------------------------------------------------------------------------
extern "C" void kernel_launch(void* const* d_in, const int* in_sizes, int n_in,
                              void* d_out, int out_size, void* d_ws, size_t ws_size,
                              hipStream_t stream) {
  const float* lc = (const float*)d_in[0];
  const float* lh = (const float*)d_in[1];
  const float* rc = (const float*)d_in[2];
  const float* rh = (const float*)d_in[3];
  const float* Wl = (const float*)d_in[4];
  const float* bl = (const float*)d_in[5];
  const float* Wr = (const float*)d_in[6];
  const float* br = (const float*)d_in[7];
  float* out = (float*)d_out;

  char* ws = (char*)d_ws;
  ushort* A  = (ushort*)ws;                                // 32 MB  bf16 [4096][4096]
  ushort* Bt = (ushort*)(ws + (size_t)32 * 1024 * 1024);   // 64 MB  bf16 [8192][4096]

  cast_concat_kernel<<<2048, 256, 0, stream>>>(lh, rh, A);
  dim3 tg(128, 32, 2);
  transpose_cast_kernel<<<tg, 256, 0, stream>>>(Wl, Wr, Bt);
  dim3 gg(64, 32);
  gemm_gate_kernel<<<gg, 256, 0, stream>>>(A, Bt, bl, br, lc, rc, out);
}